// Round 8
// baseline (726.528 us; speedup 1.0000x reference)
//
#include <hip/hip_runtime.h>
#include <stdint.h>

#define T_SEQ 8192
#define DMODEL 512
#define QKV_LD 1536   // row stride (elements) of fused QKV output

typedef __attribute__((ext_vector_type(8))) short bfx8;   // 8 bf16 (raw bits) = 4 VGPR
typedef __attribute__((ext_vector_type(4))) float fx4;    // MFMA acc

__device__ __forceinline__ unsigned short f2bf(float f) {
    uint32_t u = __float_as_uint(f);
    u += 0x7fffu + ((u >> 16) & 1u);     // round-to-nearest-even
    return (unsigned short)(u >> 16);
}
__device__ __forceinline__ float bf2f(unsigned short s) {
    return __uint_as_float(((uint32_t)s) << 16);
}

// async global->LDS, 16B per lane; LDS dest is wave-uniform base + lane*16 (HW)
__device__ __forceinline__ void gload16(const void* g, void* l) {
    __builtin_amdgcn_global_load_lds(
        (const __attribute__((address_space(1))) unsigned int*)g,
        (__attribute__((address_space(3))) unsigned int*)l,
        16, 0, 0);
}

__device__ __forceinline__ void fence_barrier() {
    asm volatile("" ::: "memory");
    __builtin_amdgcn_s_barrier();
    asm volatile("" ::: "memory");
}

// ---------------- weight conversion f32 -> bf16 ----------------
__global__ __launch_bounds__(256) void cvt_bf16_kernel(const float* __restrict__ src,
                                                       unsigned short* __restrict__ dst, int n) {
    int i = (blockIdx.x * 256 + threadIdx.x) * 8;
    if (i >= n) return;
    fx4 a = *(const fx4*)(src + i);
    fx4 b = *(const fx4*)(src + i + 4);
    bfx8 o;
    o[0] = f2bf(a[0]); o[1] = f2bf(a[1]); o[2] = f2bf(a[2]); o[3] = f2bf(a[3]);
    o[4] = f2bf(b[0]); o[5] = f2bf(b[1]); o[6] = f2bf(b[2]); o[7] = f2bf(b[3]);
    *(bfx8*)(dst + i) = o;
}

// ---------------- LayerNorm (one wave per row) ----------------
__global__ __launch_bounds__(256) void layernorm_kernel(const float* __restrict__ h,
                                                        const float* __restrict__ w,
                                                        const float* __restrict__ b,
                                                        unsigned short* __restrict__ out) {
    int wv = threadIdx.x >> 6, lane = threadIdx.x & 63;
    int row = blockIdx.x * 4 + wv;
    const float* hr = h + (size_t)row * DMODEL + lane * 8;
    fx4 x0 = *(const fx4*)hr;
    fx4 x1 = *(const fx4*)(hr + 4);
    float s  = x0[0]+x0[1]+x0[2]+x0[3]+x1[0]+x1[1]+x1[2]+x1[3];
    float ss = x0[0]*x0[0]+x0[1]*x0[1]+x0[2]*x0[2]+x0[3]*x0[3]
             + x1[0]*x1[0]+x1[1]*x1[1]+x1[2]*x1[2]+x1[3]*x1[3];
    #pragma unroll
    for (int m = 1; m < 64; m <<= 1) { s += __shfl_xor(s, m); ss += __shfl_xor(ss, m); }
    float mu  = s * (1.0f / DMODEL);
    float var = ss * (1.0f / DMODEL) - mu * mu;
    float r = rsqrtf(var + 1e-5f);
    const float* wp = w + lane * 8; const float* bp = b + lane * 8;
    fx4 w0 = *(const fx4*)wp, w1 = *(const fx4*)(wp + 4);
    fx4 b0 = *(const fx4*)bp, b1 = *(const fx4*)(bp + 4);
    bfx8 o;
    o[0] = f2bf((x0[0]-mu)*r*w0[0] + b0[0]);
    o[1] = f2bf((x0[1]-mu)*r*w0[1] + b0[1]);
    o[2] = f2bf((x0[2]-mu)*r*w0[2] + b0[2]);
    o[3] = f2bf((x0[3]-mu)*r*w0[3] + b0[3]);
    o[4] = f2bf((x1[0]-mu)*r*w1[0] + b1[0]);
    o[5] = f2bf((x1[1]-mu)*r*w1[1] + b1[1]);
    o[6] = f2bf((x1[2]-mu)*r*w1[2] + b1[2]);
    o[7] = f2bf((x1[3]-mu)*r*w1[3] + b1[3]);
    *(bfx8*)(out + (size_t)row * DMODEL + lane * 8) = o;
}

// ---------------- C = A @ B^T  (both [rows][K] bf16), 128x128 tile ----------------
template<int RESID>
__global__ __launch_bounds__(256, 2) void gemm_bt_kernel(
    const unsigned short* __restrict__ A,   // [M][K]
    const unsigned short* __restrict__ B,   // [N][K]
    unsigned short* __restrict__ Cb,
    float* __restrict__ Cf,
    const float* __restrict__ resid,
    int M, int N, int K)
{
    __shared__ unsigned short At[128 * 64];
    __shared__ unsigned short Bt[128 * 64];
    int tid = threadIdx.x;
    int wv = tid >> 6, lane = tid & 63, l15 = lane & 15, l4 = lane >> 4;
    int wr = wv >> 1, wc = wv & 1;
    int row0 = blockIdx.y * 128;
    int col0 = blockIdx.x * 128;
    fx4 acc[4][4] = {};
    const char* Abase = (const char*)(A + (size_t)row0 * K);
    const char* Bbase = (const char*)(B + (size_t)col0 * K);
    for (int kt = 0; kt < K; kt += 64) {
        #pragma unroll
        for (int ch = 0; ch < 4; ch++) {
            int bix = (ch * 256 + tid) * 16;
            int r = bix >> 7;
            int sb = (bix & 127) ^ ((r & 7) << 4);
            bfx8 va = *(const bfx8*)(Abase + (size_t)r * (K * 2) + kt * 2 + sb);
            bfx8 vb = *(const bfx8*)(Bbase + (size_t)r * (K * 2) + kt * 2 + sb);
            *(bfx8*)((char*)At + bix) = va;
            *(bfx8*)((char*)Bt + bix) = vb;
        }
        __syncthreads();
        #pragma unroll
        for (int ks = 0; ks < 2; ks++) {
            bfx8 af[4], bf[4];
            #pragma unroll
            for (int m = 0; m < 4; m++) {
                int ra = wr * 64 + m * 16 + l15;
                int ka = (ks * 64 + l4 * 16) ^ ((ra & 7) << 4);
                af[m] = *(const bfx8*)((const char*)At + ra * 128 + ka);
                int rb = wc * 64 + m * 16 + l15;
                int kb = (ks * 64 + l4 * 16) ^ ((rb & 7) << 4);
                bf[m] = *(const bfx8*)((const char*)Bt + rb * 128 + kb);
            }
            #pragma unroll
            for (int m = 0; m < 4; m++)
                #pragma unroll
                for (int n = 0; n < 4; n++)
                    acc[m][n] = __builtin_amdgcn_mfma_f32_16x16x32_bf16(af[m], bf[n], acc[m][n], 0, 0, 0);
        }
        __syncthreads();
    }
    #pragma unroll
    for (int m = 0; m < 4; m++)
        #pragma unroll
        for (int n = 0; n < 4; n++)
            #pragma unroll
            for (int r = 0; r < 4; r++) {
                int row = row0 + wr * 64 + m * 16 + l4 * 4 + r;
                int col = col0 + wc * 64 + n * 16 + l15;
                float v = acc[m][n][r];
                size_t o = (size_t)row * N + col;
                if (RESID) Cf[o] = v + resid[o];
                else       Cb[o] = f2bf(v);
            }
}

// ---------------- transpose V [T][ld] -> Vt [D][T] ----------------
__global__ __launch_bounds__(256) void transpose_kernel(const unsigned short* __restrict__ v,
                                                        unsigned short* __restrict__ vt, int ld) {
    __shared__ unsigned short tile[64][80];
    int t = threadIdx.x;
    int r0 = blockIdx.x * 64;   // T dim
    int c0 = blockIdx.y * 64;   // D dim
    int r = t >> 2, cw = (t & 3) * 16;
    const unsigned short* src = v + (size_t)(r0 + r) * ld + c0 + cw;
    bfx8 a = *(const bfx8*)src;
    bfx8 b = *(const bfx8*)(src + 8);
    #pragma unroll
    for (int j = 0; j < 8; j++) { tile[r][cw + j] = a[j]; tile[r][cw + 8 + j] = b[j]; }
    __syncthreads();
    int dc = t >> 2, rb = (t & 3) * 16;
    bfx8 o0, o1;
    #pragma unroll
    for (int j = 0; j < 8; j++) { o0[j] = tile[rb + j][dc]; o1[j] = tile[rb + 8 + j][dc]; }
    unsigned short* dst = vt + (size_t)(c0 + dc) * T_SEQ + r0 + rb;
    *(bfx8*)dst = o0;
    *(bfx8*)(dst + 8) = o1;
}

// ---------------- flash attention v6: 3 workgroups/CU ----------------
// 256 threads (4 waves), QBLK=32, KVBLK=32. R7 lesson: 1 WG/CU + lockstep
// barriers leaves ~50% idle latency. This version: LDS 42.3KB -> 3 WG/CU
// (12 waves/CU, 3 independent barrier groups cover each other's stalls).
// QK^T: wave (s,kb): rows [16s,+16), k-half [256kb,+256) -> partial S into
// Sp_lds (f32); Q is register-resident at only 8 bfx8 = 32 VGPR (no spill:
// launch_bounds(256,3) caps alloc at 170 >= ~150 demand).
// Softmax: wave pair (s,*) duplicates the reduction (reads both Sp halves,
// full 32-col row max/exp locally) -> no cross-wave exchange, no extra barrier.
// PV: wave (g,cc): rows [16g,+16), d-cols [256cc,+256); V staged into the
// K buffer (time-shared) after K reads done.
__global__ __launch_bounds__(256, 3)
void flash5_kernel(
    const unsigned short* __restrict__ q,      // rows stride QKV_LD
    const unsigned short* __restrict__ k,      // rows stride QKV_LD
    const unsigned short* __restrict__ vt,     // [DMODEL][T_SEQ]
    unsigned short* __restrict__ opart,        // [NBLK][32][512] bf16 unnormalized
    float* __restrict__ mbuf, float* __restrict__ lbuf,   // [NBLK][32]
    int CHT, int NBLK)                         // CHT = kv tiles (32 rows) per chunk
{
    __shared__ unsigned short KV_lds[32 * 512];  // 32KB: K rows(1024B) then V d-rows(64B)
    __shared__ float Sp_lds[2][32 * 32];         // 8KB partial S (per k-half)
    __shared__ unsigned short p_lds[32 * 32];    // 2KB
    __shared__ float alpha_lds[32];

    int tid = threadIdx.x;
    int wv = tid >> 6, lane = tid & 63, l15 = lane & 15, l4 = lane >> 4;

    // XCD-chunked bijective swizzle (NBLK % 8 == 0)
    int L = blockIdx.x;
    int bid = (L & 7) * (NBLK >> 3) + (L >> 3);

    // chunk-major decode: count(c) = 256 - CHT*c ; cum(c) = 256c - CHT*c(c-1)/2
    int c = 0;
    while (bid >= 256 * (c + 1) - CHT * (c + 1) * c / 2) c++;
    int qi = CHT * c + (bid - (256 * c - CHT * c * (c - 1) / 2));
    int R0 = qi * 32;
    int kv_begin = c * CHT * 32;
    int kv_end = min(kv_begin + CHT * 32, R0 + 32);
    int ntile = (kv_end - kv_begin) >> 5;

    int s = wv >> 1, kb = wv & 1;     // QK^T + softmax roles (hh == kb)
    int g = wv & 1, cc = wv >> 1;     // PV roles

    // Q fragments (registers): rows R0+16s+l15, k = kb*256 + ks*32 + l4*8
    bfx8 qf[8];
    {
        const unsigned short* qp = q + (size_t)(R0 + s * 16 + l15) * QKV_LD + kb * 256 + l4 * 8;
        #pragma unroll
        for (int ks = 0; ks < 8; ks++) qf[ks] = *(const bfx8*)(qp + ks * 32);
    }

    fx4 acc[16] = {};
    float m_run[4], l_run[4];
    #pragma unroll
    for (int r = 0; r < 4; r++) { m_run[r] = -INFINITY; l_run[r] = 0.f; }

    const float rscale = 0.044194173824159216f;  // 1/sqrt(512)

    auto stageK = [&](int kv0) {
        const char* kbp = (const char*)k + (size_t)kv0 * (QKV_LD * 2);
        #pragma unroll
        for (int j = 0; j < 8; j++) {
            int row = wv * 8 + j;                 // K row (1024B data, stride 3072B)
            int sw = (row & 7) << 4;
            const char* gp = kbp + (size_t)row * (QKV_LD * 2) + ((lane * 16) ^ sw);
            gload16(gp, (char*)KV_lds + row * 1024);
        }
    };
    auto stageV = [&](int kv0) {
        const char* vb = (const char*)vt + (size_t)kv0 * 2;
        #pragma unroll
        for (int j = 0; j < 8; j++) {
            int seg = wv * 8 + j;                 // 1KB seg = 16 d-rows of 64B
            int dr = seg * 16 + (lane >> 2);
            int sw = (dr & 3) << 4;
            const char* gp = vb + (size_t)dr * (T_SEQ * 2) + (((lane & 3) * 16) ^ sw);
            gload16(gp, (char*)KV_lds + seg * 1024);
        }
    };

    stageK(kv_begin);

    for (int it = 0; it < ntile; it++) {
        int kv0 = kv_begin + it * 32;

        asm volatile("s_waitcnt vmcnt(0)" ::: "memory");
        fence_barrier();                               // B1: K(it) staged
        __builtin_amdgcn_sched_barrier(0);

        // ---- QK^T partial (k-half kb): S[16s..+16][0..32) ----
        fx4 sf[2] = {};
        #pragma unroll
        for (int ks = 0; ks < 8; ks++) {
            #pragma unroll
            for (int n = 0; n < 2; n++) {
                int krow = n * 16 + l15;
                int kb2 = (kb * 512 + ks * 64 + l4 * 16) ^ ((krow & 7) << 4);
                bfx8 kfr = *(const bfx8*)((const char*)KV_lds + krow * 1024 + kb2);
                sf[n] = __builtin_amdgcn_mfma_f32_16x16x32_bf16(qf[ks], kfr, sf[n], 0, 0, 0);
            }
        }
        // write partial S to Sp_lds (f32, swizzled)
        #pragma unroll
        for (int n = 0; n < 2; n++)
            #pragma unroll
            for (int r = 0; r < 4; r++) {
                int row = s * 16 + l4 * 4 + r;
                int col = n * 16 + l15;
                Sp_lds[kb][row * 32 + (col ^ ((row & 7) << 2))] = sf[n][r];
            }
        asm volatile("s_waitcnt lgkmcnt(0)" ::: "memory");
        fence_barrier();                               // B2: Sp complete; K reads done

        stageV(kv0);                                   // V overwrites K region

        // ---- softmax (duplicated across the (s,*) wave pair; no exchange) ----
        float sv[2][4];
        #pragma unroll
        for (int n = 0; n < 2; n++)
            #pragma unroll
            for (int r = 0; r < 4; r++) {
                int row = s * 16 + l4 * 4 + r;
                int col = n * 16 + l15;
                int off = row * 32 + (col ^ ((row & 7) << 2));
                float x = (Sp_lds[0][off] + Sp_lds[1][off]) * rscale;
                sv[n][r] = (kv0 + col > R0 + row) ? -INFINITY : x;
            }
        float al[4];
        #pragma unroll
        for (int r = 0; r < 4; r++) {
            float x = fmaxf(sv[0][r], sv[1][r]);
            x = fmaxf(x, __shfl_xor(x, 1));
            x = fmaxf(x, __shfl_xor(x, 2));
            x = fmaxf(x, __shfl_xor(x, 4));
            x = fmaxf(x, __shfl_xor(x, 8));
            float mn = fmaxf(m_run[r], x);
            al[r] = __expf(m_run[r] - mn);       // -inf -> 0 (mn finite)
            m_run[r] = mn;
        }
        if (kb == 0 && l15 == 0) {
            #pragma unroll
            for (int r = 0; r < 4; r++) alpha_lds[s * 16 + l4 * 4 + r] = al[r];
        }
        #pragma unroll
        for (int r = 0; r < 4; r++) {
            int row = s * 16 + l4 * 4 + r;
            float p0 = __expf(sv[0][r] - m_run[r]);
            float p1 = __expf(sv[1][r] - m_run[r]);
            // this wave writes only its kb-half of P
            float pw = kb ? p1 : p0;
            int col = kb * 16 + l15;
            int pb = row * 64 + ((col * 2) ^ ((row & 3) << 4));
            *(unsigned short*)((char*)p_lds + pb) = f2bf(pw);
            float x = p0 + p1;
            x += __shfl_xor(x, 1); x += __shfl_xor(x, 2);
            x += __shfl_xor(x, 4); x += __shfl_xor(x, 8);
            l_run[r] = l_run[r] * al[r] + x;
        }
        asm volatile("s_waitcnt lgkmcnt(0) vmcnt(0)" ::: "memory");
        fence_barrier();                               // B3: P+alpha ready; V staged
        __builtin_amdgcn_sched_barrier(0);

        // ---- rescale O, then PV: rows [16g,+16), d-cols [256cc,+256) ----
        float apv[4];
        #pragma unroll
        for (int r = 0; r < 4; r++) apv[r] = alpha_lds[g * 16 + l4 * 4 + r];
        #pragma unroll
        for (int n = 0; n < 16; n++)
            #pragma unroll
            for (int r = 0; r < 4; r++) acc[n][r] *= apv[r];
        bfx8 pa;
        {
            int prow = g * 16 + l15;
            pa = *(const bfx8*)((const char*)p_lds + prow * 64 + ((l4 * 16) ^ ((prow & 3) << 4)));
        }
        #pragma unroll
        for (int n = 0; n < 16; n++) {
            int dr = cc * 256 + n * 16 + l15;
            int vb2 = (l4 * 16) ^ ((dr & 3) << 4);
            bfx8 vfr = *(const bfx8*)((const char*)KV_lds + dr * 64 + vb2);
            acc[n] = __builtin_amdgcn_mfma_f32_16x16x32_bf16(pa, vfr, acc[n], 0, 0, 0);
        }
        asm volatile("s_waitcnt lgkmcnt(0)" ::: "memory");
        fence_barrier();                               // B4: V/p reads done

        if (it + 1 < ntile) stageK(kv0 + 32);          // exposed latency covered by other WGs
    }

    // ---- store unnormalized O partial (PV roles) ----
    #pragma unroll
    for (int n = 0; n < 16; n++)
        #pragma unroll
        for (int r = 0; r < 4; r++) {
            int rowl = g * 16 + l4 * 4 + r;
            int col = cc * 256 + n * 16 + l15;
            opart[((size_t)bid * 32 + rowl) * DMODEL + col] = f2bf(acc[n][r]);
        }
    // ---- m,l store (softmax roles, kb==0 wave of each pair) ----
    if (kb == 0 && l15 == 0) {
        #pragma unroll
        for (int r = 0; r < 4; r++) {
            int rowl = s * 16 + l4 * 4 + r;
            lbuf[(size_t)bid * 32 + rowl] = l_run[r];
            mbuf[(size_t)bid * 32 + rowl] = m_run[r];
        }
    }
}

// ---------------- combine partials across KV chunks ----------------
__global__ __launch_bounds__(256) void combine3_kernel(
    const unsigned short* __restrict__ opart,
    const float* __restrict__ mbuf, const float* __restrict__ lbuf,
    unsigned short* __restrict__ attn, int CHT)
{
    int tid = threadIdx.x;
    int row = blockIdx.x * 4 + (tid >> 6);
    int col = (tid & 63) * 8;
    int qi = row >> 5, rowl = row & 31;
    int nch = qi / CHT + 1;
    float M = -INFINITY;
    for (int c = 0; c < nch; c++) {
        int pidx = 256 * c - CHT * c * (c - 1) / 2 + (qi - CHT * c);
        M = fmaxf(M, mbuf[(size_t)pidx * 32 + rowl]);
    }
    float L = 0.f;
    float accv[8] = {0.f,0.f,0.f,0.f,0.f,0.f,0.f,0.f};
    for (int c = 0; c < nch; c++) {
        int pidx = 256 * c - CHT * c * (c - 1) / 2 + (qi - CHT * c);
        float e = __expf(mbuf[(size_t)pidx * 32 + rowl] - M);
        L += lbuf[(size_t)pidx * 32 + rowl] * e;
        bfx8 v = *(const bfx8*)(opart + ((size_t)pidx * 32 + rowl) * DMODEL + col);
        #pragma unroll
        for (int j = 0; j < 8; j++) accv[j] += e * bf2f((unsigned short)v[j]);
    }
    float invL = 1.0f / L;
    bfx8 o;
    #pragma unroll
    for (int j = 0; j < 8; j++) o[j] = f2bf(accv[j] * invL);
    *(bfx8*)(attn + (size_t)row * DMODEL + col) = o;
}

// ---------------- host launcher ----------------
extern "C" void kernel_launch(void* const* d_in, const int* in_sizes, int n_in,
                              void* d_out, int out_size, void* d_ws, size_t ws_size,
                              hipStream_t stream) {
    const float* h   = (const float*)d_in[0];
    const float* lnw = (const float*)d_in[1];
    const float* lnb = (const float*)d_in[2];
    const float* wq  = (const float*)d_in[3];
    const float* wk  = (const float*)d_in[4];
    const float* wv  = (const float*)d_in[5];
    const float* wo  = (const float*)d_in[6];
    float* out = (float*)d_out;

    char* ws = (char*)d_ws;
    size_t off = 0;
    auto alloc = [&](size_t bytes) {
        char* p = ws + off;
        off += (bytes + 255) & ~(size_t)255;
        return p;
    };
    const size_t TD2 = (size_t)T_SEQ * DMODEL * 2;
    const size_t W2  = (size_t)DMODEL * DMODEL * 2;
    unsigned short* hn   = (unsigned short*)alloc(TD2);
    unsigned short* wqkv = (unsigned short*)alloc(3 * W2);   // stacked [wq;wk;wv]
    unsigned short* wob  = (unsigned short*)alloc(W2);
    unsigned short* qkvb = (unsigned short*)alloc((size_t)T_SEQ * QKV_LD * 2);  // fused QKV [T][1536]
    unsigned short* vtb  = (unsigned short*)alloc(TD2);
    unsigned short* attnb= (unsigned short*)alloc(TD2);

    // KV chunking: CHT kv-tiles (32 rows each) per chunk; 256 q-tiles of 32 rows.
    // NBLK = sum_{qi=0..255} ceil((qi+1)/CHT); opart = NBLK*32*512*2 bytes.
    int CHT = 16, NBLK = 2176;   // 16*(1+..+16) = 2176, %8==0
    {
        size_t need = off + 2 * (((size_t)2176 * 32 * 4 + 255) & ~(size_t)255)
                    + (((size_t)2176 * 32 * 512 * 2 + 255) & ~(size_t)255);
        if (need > ws_size) { CHT = 32; NBLK = 1152; }  // 32*(1+..+8)=1152, %8==0
    }
    float* mbuf = (float*)alloc((size_t)NBLK * 32 * 4);
    float* lbuf = (float*)alloc((size_t)NBLK * 32 * 4);
    unsigned short* opart = (unsigned short*)alloc((size_t)NBLK * 32 * 512 * 2);

    cvt_bf16_kernel<<<dim3(128), dim3(256), 0, stream>>>(wq, wqkv,                   DMODEL * DMODEL);
    cvt_bf16_kernel<<<dim3(128), dim3(256), 0, stream>>>(wk, wqkv + DMODEL*DMODEL,   DMODEL * DMODEL);
    cvt_bf16_kernel<<<dim3(128), dim3(256), 0, stream>>>(wv, wqkv + 2*DMODEL*DMODEL, DMODEL * DMODEL);
    cvt_bf16_kernel<<<dim3(128), dim3(256), 0, stream>>>(wo, wob, DMODEL * DMODEL);

    layernorm_kernel<<<dim3(T_SEQ / 4), dim3(256), 0, stream>>>(h, lnw, lnb, hn);

    // fused QKV projection: [T,512] @ [1536,512]^T -> [T,1536]
    gemm_bt_kernel<0><<<dim3(QKV_LD / 128, T_SEQ / 128), dim3(256), 0, stream>>>(
        hn, wqkv, qkvb, nullptr, nullptr, T_SEQ, QKV_LD, DMODEL);

    // V (cols 1024..1535 of qkvb) -> Vt [512][T]
    transpose_kernel<<<dim3(T_SEQ / 64, DMODEL / 64), dim3(256), 0, stream>>>(
        qkvb + 2 * DMODEL, vtb, QKV_LD);

    flash5_kernel<<<dim3(NBLK), dim3(256), 0, stream>>>(
        qkvb, qkvb + DMODEL, vtb, opart, mbuf, lbuf, CHT, NBLK);

    combine3_kernel<<<dim3(T_SEQ / 4), dim3(256), 0, stream>>>(opart, mbuf, lbuf, attnb, CHT);

    gemm_bt_kernel<1><<<dim3(DMODEL / 128, T_SEQ / 128), dim3(256), 0, stream>>>(
        attnb, wob, nullptr, out, h, T_SEQ, DMODEL, DMODEL);
}

// Round 9
// 381.979 us; speedup vs baseline: 1.9020x; 1.9020x over previous
//
#include <hip/hip_runtime.h>
#include <stdint.h>

#define T_SEQ 8192
#define DMODEL 512
#define QKV_LD 1536   // row stride (elements) of fused QKV output

typedef __attribute__((ext_vector_type(8))) short bfx8;     // 8 bf16 (raw bits) = 4 VGPR
typedef __attribute__((ext_vector_type(4))) float fx4;      // 16x16 MFMA acc
typedef __attribute__((ext_vector_type(16))) float f32x16;  // 32x32 MFMA acc

__device__ __forceinline__ unsigned short f2bf(float f) {
    uint32_t u = __float_as_uint(f);
    u += 0x7fffu + ((u >> 16) & 1u);     // round-to-nearest-even
    return (unsigned short)(u >> 16);
}
__device__ __forceinline__ float bf2f(unsigned short s) {
    return __uint_as_float(((uint32_t)s) << 16);
}

// async global->LDS, 16B per lane; LDS dest is wave-uniform base + lane*16 (HW)
__device__ __forceinline__ void gload16(const void* g, void* l) {
    __builtin_amdgcn_global_load_lds(
        (const __attribute__((address_space(1))) unsigned int*)g,
        (__attribute__((address_space(3))) unsigned int*)l,
        16, 0, 0);
}

__device__ __forceinline__ void fence_barrier() {
    asm volatile("" ::: "memory");
    __builtin_amdgcn_s_barrier();
    asm volatile("" ::: "memory");
}

// ---------------- weight conversion f32 -> bf16 ----------------
__global__ __launch_bounds__(256) void cvt_bf16_kernel(const float* __restrict__ src,
                                                       unsigned short* __restrict__ dst, int n) {
    int i = (blockIdx.x * 256 + threadIdx.x) * 8;
    if (i >= n) return;
    fx4 a = *(const fx4*)(src + i);
    fx4 b = *(const fx4*)(src + i + 4);
    bfx8 o;
    o[0] = f2bf(a[0]); o[1] = f2bf(a[1]); o[2] = f2bf(a[2]); o[3] = f2bf(a[3]);
    o[4] = f2bf(b[0]); o[5] = f2bf(b[1]); o[6] = f2bf(b[2]); o[7] = f2bf(b[3]);
    *(bfx8*)(dst + i) = o;
}

// ---------------- LayerNorm (one wave per row) ----------------
__global__ __launch_bounds__(256) void layernorm_kernel(const float* __restrict__ h,
                                                        const float* __restrict__ w,
                                                        const float* __restrict__ b,
                                                        unsigned short* __restrict__ out) {
    int wv = threadIdx.x >> 6, lane = threadIdx.x & 63;
    int row = blockIdx.x * 4 + wv;
    const float* hr = h + (size_t)row * DMODEL + lane * 8;
    fx4 x0 = *(const fx4*)hr;
    fx4 x1 = *(const fx4*)(hr + 4);
    float s  = x0[0]+x0[1]+x0[2]+x0[3]+x1[0]+x1[1]+x1[2]+x1[3];
    float ss = x0[0]*x0[0]+x0[1]*x0[1]+x0[2]*x0[2]+x0[3]*x0[3]
             + x1[0]*x1[0]+x1[1]*x1[1]+x1[2]*x1[2]+x1[3]*x1[3];
    #pragma unroll
    for (int m = 1; m < 64; m <<= 1) { s += __shfl_xor(s, m); ss += __shfl_xor(ss, m); }
    float mu  = s * (1.0f / DMODEL);
    float var = ss * (1.0f / DMODEL) - mu * mu;
    float r = rsqrtf(var + 1e-5f);
    const float* wp = w + lane * 8; const float* bp = b + lane * 8;
    fx4 w0 = *(const fx4*)wp, w1 = *(const fx4*)(wp + 4);
    fx4 b0 = *(const fx4*)bp, b1 = *(const fx4*)(bp + 4);
    bfx8 o;
    o[0] = f2bf((x0[0]-mu)*r*w0[0] + b0[0]);
    o[1] = f2bf((x0[1]-mu)*r*w0[1] + b0[1]);
    o[2] = f2bf((x0[2]-mu)*r*w0[2] + b0[2]);
    o[3] = f2bf((x0[3]-mu)*r*w0[3] + b0[3]);
    o[4] = f2bf((x1[0]-mu)*r*w1[0] + b1[0]);
    o[5] = f2bf((x1[1]-mu)*r*w1[1] + b1[1]);
    o[6] = f2bf((x1[2]-mu)*r*w1[2] + b1[2]);
    o[7] = f2bf((x1[3]-mu)*r*w1[3] + b1[3]);
    *(bfx8*)(out + (size_t)row * DMODEL + lane * 8) = o;
}

// ---------------- C = A @ B^T  (both [rows][K] bf16), 128x128 tile ----------------
template<int RESID>
__global__ __launch_bounds__(256, 2) void gemm_bt_kernel(
    const unsigned short* __restrict__ A,   // [M][K]
    const unsigned short* __restrict__ B,   // [N][K]
    unsigned short* __restrict__ Cb,
    float* __restrict__ Cf,
    const float* __restrict__ resid,
    int M, int N, int K)
{
    __shared__ unsigned short At[128 * 64];
    __shared__ unsigned short Bt[128 * 64];
    int tid = threadIdx.x;
    int wv = tid >> 6, lane = tid & 63, l15 = lane & 15, l4 = lane >> 4;
    int wr = wv >> 1, wc = wv & 1;
    int row0 = blockIdx.y * 128;
    int col0 = blockIdx.x * 128;
    fx4 acc[4][4] = {};
    const char* Abase = (const char*)(A + (size_t)row0 * K);
    const char* Bbase = (const char*)(B + (size_t)col0 * K);
    for (int kt = 0; kt < K; kt += 64) {
        #pragma unroll
        for (int ch = 0; ch < 4; ch++) {
            int bix = (ch * 256 + tid) * 16;
            int r = bix >> 7;
            int sb = (bix & 127) ^ ((r & 7) << 4);
            bfx8 va = *(const bfx8*)(Abase + (size_t)r * (K * 2) + kt * 2 + sb);
            bfx8 vb = *(const bfx8*)(Bbase + (size_t)r * (K * 2) + kt * 2 + sb);
            *(bfx8*)((char*)At + bix) = va;
            *(bfx8*)((char*)Bt + bix) = vb;
        }
        __syncthreads();
        #pragma unroll
        for (int ks = 0; ks < 2; ks++) {
            bfx8 af[4], bf[4];
            #pragma unroll
            for (int m = 0; m < 4; m++) {
                int ra = wr * 64 + m * 16 + l15;
                int ka = (ks * 64 + l4 * 16) ^ ((ra & 7) << 4);
                af[m] = *(const bfx8*)((const char*)At + ra * 128 + ka);
                int rb = wc * 64 + m * 16 + l15;
                int kb = (ks * 64 + l4 * 16) ^ ((rb & 7) << 4);
                bf[m] = *(const bfx8*)((const char*)Bt + rb * 128 + kb);
            }
            #pragma unroll
            for (int m = 0; m < 4; m++)
                #pragma unroll
                for (int n = 0; n < 4; n++)
                    acc[m][n] = __builtin_amdgcn_mfma_f32_16x16x32_bf16(af[m], bf[n], acc[m][n], 0, 0, 0);
        }
        __syncthreads();
    }
    #pragma unroll
    for (int m = 0; m < 4; m++)
        #pragma unroll
        for (int n = 0; n < 4; n++)
            #pragma unroll
            for (int r = 0; r < 4; r++) {
                int row = row0 + wr * 64 + m * 16 + l4 * 4 + r;
                int col = col0 + wc * 64 + n * 16 + l15;
                float v = acc[m][n][r];
                size_t o = (size_t)row * N + col;
                if (RESID) Cf[o] = v + resid[o];
                else       Cb[o] = f2bf(v);
            }
}

// ---------------- transpose V [T][ld] -> Vt [D][T] ----------------
__global__ __launch_bounds__(256) void transpose_kernel(const unsigned short* __restrict__ v,
                                                        unsigned short* __restrict__ vt, int ld) {
    __shared__ unsigned short tile[64][80];
    int t = threadIdx.x;
    int r0 = blockIdx.x * 64;   // T dim
    int c0 = blockIdx.y * 64;   // D dim
    int r = t >> 2, cw = (t & 3) * 16;
    const unsigned short* src = v + (size_t)(r0 + r) * ld + c0 + cw;
    bfx8 a = *(const bfx8*)src;
    bfx8 b = *(const bfx8*)(src + 8);
    #pragma unroll
    for (int j = 0; j < 8; j++) { tile[r][cw + j] = a[j]; tile[r][cw + 8 + j] = b[j]; }
    __syncthreads();
    int dc = t >> 2, rb = (t & 3) * 16;
    bfx8 o0, o1;
    #pragma unroll
    for (int j = 0; j < 8; j++) { o0[j] = tile[rb + j][dc]; o1[j] = tile[rb + 8 + j][dc]; }
    unsigned short* dst = vt + (size_t)(c0 + dc) * T_SEQ + r0 + rb;
    *(bfx8*)dst = o0;
    *(bfx8*)(dst + 8) = o1;
}

// ---------------- flash attention v7: producer/consumer wave split ----------------
// 512 threads, 8 waves: waves 0-3 = S-waves (Q in regs 64 VGPR, no acc):
// QK^T(t)+softmax(t). Waves 4-7 = O-waves (acc 64 AGPR, no Q): PV(t-1).
// Phase A (B1..B2): S: QK^T(t) from K_lds; O: rescale+PV(t-1) from V_lds/p_lds.
// Phase B (B2..B1'): stage V(t)->V_lds, K(t+1)->K_lds (all waves); S: softmax.
// 2 barriers/iter. QBLK=32, KVBLK=64. PV uses 32x32x16 MFMA (2x FLOP/LDS-byte,
// pa reused across 4 d-subtiles). LDS: K 64KB + Vt 64KB + P 4KB ~= 133KB, 1 WG/CU
// (intra-block wave overlap replaces multi-WG). Arch-VGPR demand ~110 + 64 AGPR
// = the R7 shape that allocated cleanly (spill tripwire: WRITE_SIZE >> 72MB).
__global__ __launch_bounds__(512)
void flash6_kernel(
    const unsigned short* __restrict__ q,      // rows stride QKV_LD
    const unsigned short* __restrict__ k,      // rows stride QKV_LD
    const unsigned short* __restrict__ vt,     // [DMODEL][T_SEQ]
    unsigned short* __restrict__ opart,        // [NBLK][32][512] bf16 unnormalized
    float* __restrict__ mbuf, float* __restrict__ lbuf,   // [NBLK][32]
    int CB, int NBLK)                          // CB = kv tiles (64 rows) per chunk
{
    __shared__ unsigned short K_lds[64 * 512];   // 64KB, rows 1024B, XOR swizzled
    __shared__ unsigned short V_lds[512 * 64];   // 64KB, d-rows 128B, XOR swizzled
    __shared__ unsigned short p_lds[32 * 64];    // 4KB, rows 128B, XOR swizzled
    __shared__ float red_lds[2][2][16];
    __shared__ float alpha_lds[32];

    int tid = threadIdx.x;
    int wv = tid >> 6, lane = tid & 63, l15 = lane & 15, l4 = lane >> 4;
    int l31 = lane & 31, hi = lane >> 5;
    bool isS = wv < 4;

    // XCD-chunked bijective swizzle (NBLK % 8 == 0)
    int L = blockIdx.x;
    int bid = (L & 7) * (NBLK >> 3) + (L >> 3);

    // chunk-major decode over 256 q-tiles (32 rows) and kv chunks of CB 64-row tiles:
    // count(c) = 256 - 2*CB*c ; cum(c) = 256c - CB*c*(c-1)
    int c = 0;
    while (bid >= 256 * (c + 1) - CB * (c + 1) * c) c++;
    int qi = 2 * CB * c + (bid - (256 * c - CB * c * (c - 1)));
    int R0 = qi * 32;
    int kv_begin = c * CB * 64;
    int kv_end = min(kv_begin + CB * 64, R0 + 32);
    int ntile = (kv_end - kv_begin + 63) >> 6;

    int s = wv >> 1, hh = wv & 1;   // S-wave roles (wv 0..3): rows 16s, cols 32hh
    int cc = wv - 4;                // O-wave role: d-cols [128cc, +128)

    const float rscale = 0.044194173824159216f;  // 1/sqrt(512)

    // S-wave state: Q fragments, rows R0+16s+l15, k = ks*32 + l4*8 + j
    bfx8 qf[16];
    float m_run[4], l_half[4];
    // O-wave state: acc for rows 0..31 x d-cols [128cc..+128): 4 subtiles 32x32
    f32x16 acc0 = {}, acc1 = {}, acc2 = {}, acc3 = {};

    if (isS) {
        const unsigned short* qp = q + (size_t)(R0 + s * 16 + l15) * QKV_LD + l4 * 8;
        #pragma unroll
        for (int ks = 0; ks < 16; ks++) qf[ks] = *(const bfx8*)(qp + ks * 32);
        #pragma unroll
        for (int r = 0; r < 4; r++) { m_run[r] = -INFINITY; l_half[r] = 0.f; }
    }

    auto stageK = [&](int kv0) {
        const char* kbp = (const char*)k + (size_t)kv0 * (QKV_LD * 2);
        #pragma unroll
        for (int j = 0; j < 8; j++) {
            int row = wv * 8 + j;                 // K row (1024B data, stride 3072B)
            int sw = (row & 7) << 4;
            const char* gp = kbp + (size_t)row * (QKV_LD * 2) + ((lane * 16) ^ sw);
            gload16(gp, (char*)K_lds + row * 1024);
        }
    };
    auto stageV = [&](int kv0) {
        const char* vb = (const char*)vt + (size_t)kv0 * 2;
        #pragma unroll
        for (int j = 0; j < 8; j++) {
            int seg = wv * 8 + j;                 // 1KB seg = 8 d-rows of 128B
            int dr = seg * 8 + (lane >> 3);
            int sw = (dr & 7) << 4;
            const char* gp = vb + (size_t)dr * (T_SEQ * 2) + (((lane & 7) * 16) ^ sw);
            gload16(gp, (char*)V_lds + seg * 1024);
        }
    };

    stageK(kv_begin);

    float sv[2][4];
    for (int it = 0; it <= ntile; it++) {
        int kv0 = kv_begin + it * 64;

        asm volatile("s_waitcnt vmcnt(0) lgkmcnt(0)" ::: "memory");
        fence_barrier();                               // B1: K(it), V(it-1), P(it-1) ready
        __builtin_amdgcn_sched_barrier(0);

        // ================= PHASE A =================
        if (isS) {
            if (it < ntile) {
                // QK^T: S[16s..+16][32hh + 16n + l15], k = 512
                fx4 sf[2] = {};
                #pragma unroll
                for (int ks = 0; ks < 16; ks++) {
                    #pragma unroll
                    for (int n = 0; n < 2; n++) {
                        int krow = hh * 32 + n * 16 + l15;
                        int kb2 = (ks * 64 + l4 * 16) ^ ((krow & 7) << 4);
                        bfx8 kfr = *(const bfx8*)((const char*)K_lds + krow * 1024 + kb2);
                        sf[n] = __builtin_amdgcn_mfma_f32_16x16x32_bf16(qf[ks], kfr, sf[n], 0, 0, 0);
                    }
                }
                #pragma unroll
                for (int n = 0; n < 2; n++) {
                    int col = kv0 + hh * 32 + n * 16 + l15;
                    #pragma unroll
                    for (int r = 0; r < 4; r++) {
                        int row = R0 + s * 16 + l4 * 4 + r;
                        sv[n][r] = (col > row) ? -INFINITY : sf[n][r] * rscale;
                    }
                }
                #pragma unroll
                for (int r = 0; r < 4; r++) {
                    float x = fmaxf(sv[0][r], sv[1][r]);
                    x = fmaxf(x, __shfl_xor(x, 1));
                    x = fmaxf(x, __shfl_xor(x, 2));
                    x = fmaxf(x, __shfl_xor(x, 4));
                    x = fmaxf(x, __shfl_xor(x, 8));
                    if (l15 == 0) red_lds[s][hh][l4 * 4 + r] = x;
                }
            }
        } else {
            if (it > 0) {
                // rescale by alpha(it-1), then O += P(it-1) @ V(it-1)  [32x32x16]
                fx4 apv[4];
                #pragma unroll
                for (int r8 = 0; r8 < 4; r8++)
                    apv[r8] = *(const fx4*)&alpha_lds[r8 * 8 + hi * 4];
                #pragma unroll
                for (int g = 0; g < 16; g++) {
                    float a = apv[g >> 2][g & 3];
                    acc0[g] *= a; acc1[g] *= a; acc2[g] *= a; acc3[g] *= a;
                }
                #pragma unroll
                for (int kstep = 0; kstep < 4; kstep++) {
                    int pb = l31 * 128 + ((kstep * 32 + hi * 16) ^ ((l31 & 7) << 4));
                    bfx8 pa = *(const bfx8*)((const char*)p_lds + pb);
                    int d0 = cc * 128 + l31;
                    #pragma unroll
                    for (int sub = 0; sub < 4; sub++) {
                        int d = d0 + sub * 32;
                        int vb2 = (kstep * 32 + hi * 16) ^ ((d & 7) << 4);
                        bfx8 vfr = *(const bfx8*)((const char*)V_lds + d * 128 + vb2);
                        if (sub == 0) acc0 = __builtin_amdgcn_mfma_f32_32x32x16_bf16(pa, vfr, acc0, 0, 0, 0);
                        if (sub == 1) acc1 = __builtin_amdgcn_mfma_f32_32x32x16_bf16(pa, vfr, acc1, 0, 0, 0);
                        if (sub == 2) acc2 = __builtin_amdgcn_mfma_f32_32x32x16_bf16(pa, vfr, acc2, 0, 0, 0);
                        if (sub == 3) acc3 = __builtin_amdgcn_mfma_f32_32x32x16_bf16(pa, vfr, acc3, 0, 0, 0);
                    }
                }
            }
        }
        if (it == ntile) break;

        asm volatile("s_waitcnt lgkmcnt(0)" ::: "memory");
        fence_barrier();                               // B2: K/V/P reads done, red ready
        __builtin_amdgcn_sched_barrier(0);

        // ================= PHASE B =================
        stageV(kv0);                                   // V(it) overwrites V(it-1)
        if (it + 1 < ntile) stageK(kv0 + 64);          // K(it+1) overwrites K(it)

        if (isS) {
            // softmax(it): both hh waves duplicate row stats (no exchange barrier)
            fx4 m0 = *(const fx4*)&red_lds[s][0][l4 * 4];
            fx4 m1 = *(const fx4*)&red_lds[s][1][l4 * 4];
            float al[4];
            #pragma unroll
            for (int r = 0; r < 4; r++) {
                float mn = fmaxf(m_run[r], fmaxf(m0[r], m1[r]));
                al[r] = __expf(m_run[r] - mn);   // -inf -> 0 (mn finite)
                m_run[r] = mn;
            }
            if (hh == 0 && l15 == 0) {
                #pragma unroll
                for (int r = 0; r < 4; r++) alpha_lds[s * 16 + l4 * 4 + r] = al[r];
            }
            float psum[4] = {0.f, 0.f, 0.f, 0.f};
            #pragma unroll
            for (int n = 0; n < 2; n++)
                #pragma unroll
                for (int r = 0; r < 4; r++) {
                    float p = __expf(sv[n][r] - m_run[r]);
                    int prow = s * 16 + l4 * 4 + r;
                    int col = hh * 32 + n * 16 + l15;
                    int pb = prow * 128 + ((col * 2) ^ ((prow & 7) << 4));
                    *(unsigned short*)((char*)p_lds + pb) = f2bf(p);
                    psum[r] += p;
                }
            #pragma unroll
            for (int r = 0; r < 4; r++) {
                float x = psum[r];
                x += __shfl_xor(x, 1); x += __shfl_xor(x, 2);
                x += __shfl_xor(x, 4); x += __shfl_xor(x, 8);
                l_half[r] = l_half[r] * al[r] + x;
            }
        }
    }

    // ---- epilogue ----
    if (!isS) {
        #pragma unroll
        for (int g = 0; g < 16; g++) {
            int row = (g & 3) + 8 * (g >> 2) + 4 * hi;
            size_t base = ((size_t)bid * 32 + row) * DMODEL + cc * 128 + l31;
            opart[base]      = f2bf(acc0[g]);
            opart[base + 32] = f2bf(acc1[g]);
            opart[base + 64] = f2bf(acc2[g]);
            opart[base + 96] = f2bf(acc3[g]);
        }
    }
    if (isS && l15 == 0) {
        #pragma unroll
        for (int r = 0; r < 4; r++) red_lds[s][hh][l4 * 4 + r] = l_half[r];
    }
    __syncthreads();
    if (isS && hh == 0 && l15 == 0) {
        #pragma unroll
        for (int r = 0; r < 4; r++) {
            int rr = l4 * 4 + r;
            lbuf[(size_t)bid * 32 + s * 16 + rr] = red_lds[s][0][rr] + red_lds[s][1][rr];
            mbuf[(size_t)bid * 32 + s * 16 + rr] = m_run[r];
        }
    }
}

// ---------------- combine partials across KV chunks ----------------
__global__ __launch_bounds__(256) void combine4_kernel(
    const unsigned short* __restrict__ opart,
    const float* __restrict__ mbuf, const float* __restrict__ lbuf,
    unsigned short* __restrict__ attn, int CB)
{
    int tid = threadIdx.x;
    int row = blockIdx.x * 4 + (tid >> 6);
    int col = (tid & 63) * 8;
    int qi = row >> 5, rowl = row & 31;
    int nch = qi / (2 * CB) + 1;
    float M = -INFINITY;
    for (int c = 0; c < nch; c++) {
        int pidx = 256 * c - CB * c * (c - 1) + (qi - 2 * CB * c);
        M = fmaxf(M, mbuf[(size_t)pidx * 32 + rowl]);
    }
    float L = 0.f;
    float accv[8] = {0.f,0.f,0.f,0.f,0.f,0.f,0.f,0.f};
    for (int c = 0; c < nch; c++) {
        int pidx = 256 * c - CB * c * (c - 1) + (qi - 2 * CB * c);
        float e = __expf(mbuf[(size_t)pidx * 32 + rowl] - M);
        L += lbuf[(size_t)pidx * 32 + rowl] * e;
        bfx8 v = *(const bfx8*)(opart + ((size_t)pidx * 32 + rowl) * DMODEL + col);
        #pragma unroll
        for (int j = 0; j < 8; j++) accv[j] += e * bf2f((unsigned short)v[j]);
    }
    float invL = 1.0f / L;
    bfx8 o;
    #pragma unroll
    for (int j = 0; j < 8; j++) o[j] = f2bf(accv[j] * invL);
    *(bfx8*)(attn + (size_t)row * DMODEL + col) = o;
}

// ---------------- host launcher ----------------
extern "C" void kernel_launch(void* const* d_in, const int* in_sizes, int n_in,
                              void* d_out, int out_size, void* d_ws, size_t ws_size,
                              hipStream_t stream) {
    const float* h   = (const float*)d_in[0];
    const float* lnw = (const float*)d_in[1];
    const float* lnb = (const float*)d_in[2];
    const float* wq  = (const float*)d_in[3];
    const float* wk  = (const float*)d_in[4];
    const float* wv  = (const float*)d_in[5];
    const float* wo  = (const float*)d_in[6];
    float* out = (float*)d_out;

    char* ws = (char*)d_ws;
    size_t off = 0;
    auto alloc = [&](size_t bytes) {
        char* p = ws + off;
        off += (bytes + 255) & ~(size_t)255;
        return p;
    };
    const size_t TD2 = (size_t)T_SEQ * DMODEL * 2;
    const size_t W2  = (size_t)DMODEL * DMODEL * 2;
    unsigned short* hn   = (unsigned short*)alloc(TD2);
    unsigned short* wqkv = (unsigned short*)alloc(3 * W2);   // stacked [wq;wk;wv]
    unsigned short* wob  = (unsigned short*)alloc(W2);
    unsigned short* qkvb = (unsigned short*)alloc((size_t)T_SEQ * QKV_LD * 2);  // fused QKV
    unsigned short* vtb  = (unsigned short*)alloc(TD2);
    unsigned short* attnb= (unsigned short*)alloc(TD2);

    // chunking: CB kv-tiles (64 rows) per chunk; 256 q-tiles of 32 rows.
    // NBLK = sum_{qi=0..255} (qi/(2*CB)+1)
    int CB = 8, NBLK = 2176;     // 16*(1+..+16) = 2176, %8==0
    {
        size_t need = off + 2 * (((size_t)2176 * 32 * 4 + 255) & ~(size_t)255)
                    + (((size_t)2176 * 32 * 512 * 2 + 255) & ~(size_t)255);
        if (need > ws_size) { CB = 16; NBLK = 1152; }  // 32*(1+..+8)=1152, %8==0
    }
    float* mbuf = (float*)alloc((size_t)NBLK * 32 * 4);
    float* lbuf = (float*)alloc((size_t)NBLK * 32 * 4);
    unsigned short* opart = (unsigned short*)alloc((size_t)NBLK * 32 * 512 * 2);

    cvt_bf16_kernel<<<dim3(128), dim3(256), 0, stream>>>(wq, wqkv,                   DMODEL * DMODEL);
    cvt_bf16_kernel<<<dim3(128), dim3(256), 0, stream>>>(wk, wqkv + DMODEL*DMODEL,   DMODEL * DMODEL);
    cvt_bf16_kernel<<<dim3(128), dim3(256), 0, stream>>>(wv, wqkv + 2*DMODEL*DMODEL, DMODEL * DMODEL);
    cvt_bf16_kernel<<<dim3(128), dim3(256), 0, stream>>>(wo, wob, DMODEL * DMODEL);

    layernorm_kernel<<<dim3(T_SEQ / 4), dim3(256), 0, stream>>>(h, lnw, lnb, hn);

    gemm_bt_kernel<0><<<dim3(QKV_LD / 128, T_SEQ / 128), dim3(256), 0, stream>>>(
        hn, wqkv, qkvb, nullptr, nullptr, T_SEQ, QKV_LD, DMODEL);

    transpose_kernel<<<dim3(T_SEQ / 64, DMODEL / 64), dim3(256), 0, stream>>>(
        qkvb + 2 * DMODEL, vtb, QKV_LD);

    flash6_kernel<<<dim3(NBLK), dim3(512), 0, stream>>>(
        qkvb, qkvb + DMODEL, vtb, opart, mbuf, lbuf, CB, NBLK);

    combine4_kernel<<<dim3(T_SEQ / 4), dim3(256), 0, stream>>>(opart, mbuf, lbuf, attnb, CB);

    gemm_bt_kernel<1><<<dim3(DMODEL / 128, T_SEQ / 128), dim3(256), 0, stream>>>(
        attnb, wob, nullptr, out, h, T_SEQ, DMODEL, DMODEL);
}